// Round 3
// baseline (96.515 us; speedup 1.0000x reference)
//
#include <hip/hip_runtime.h>
#include <hip/hip_bf16.h>

typedef __bf16 bf16;
typedef __bf16 bf16x4 __attribute__((ext_vector_type(4)));
typedef __bf16 bf16x8 __attribute__((ext_vector_type(8)));
typedef float  f32x4  __attribute__((ext_vector_type(4)));

#define HID   128
#define BSZ   8
#define CDIM  512
#define QDIM  64
#define LDH   136   // LDS leading dim (bf16): 272 B rows -> 16B-aligned, breaks pow2 bank stride

// One WG per (b,q). W_eff[k][d] = w_h[k][d] + u[d]*w_hu[k][d] folds h_proj +
// hu_proj into one per-(b,q) GEMM: l1 = relu(h @ W_eff^T + bias),
// bias[k] = b1[k] + u.w_u[k] (fp32 exact). out = relu(l1 @ w2 + b2) fused.
// After the one-time W_eff build: ZERO barriers, zero LDS traffic except the
// lifetime-cached B fragments; A streamed straight from global fp32 h
// (L2-resident) with inline bf16 cvt. No d_ws usage (keeps poison-fill fast).
__global__ __launch_bounds__(256, 2)
void sim_kernel(const float* __restrict__ hptr,
                const float* __restrict__ uptr,
                const float* __restrict__ w1,
                const float* __restrict__ b1,
                const float* __restrict__ w2,
                const float* __restrict__ b2,
                float* __restrict__ out)
{
    __shared__ bf16  weff[HID * LDH];   // [k_out][d]
    __shared__ float ush[HID];
    __shared__ float bias_sh[HID];
    __shared__ float w2sh[HID];

    const int t  = threadIdx.x;
    const int bi = blockIdx.x >> 6;
    const int qi = blockIdx.x & 63;

    const float* uvec = uptr + (bi * QDIM + qi) * HID;

    if (t < HID) {
        ush[t]  = uvec[t];
        w2sh[t] = w2[t];
    }
    __syncthreads();

    // ---- build W_eff (bf16): 2 threads per k-row, 64 d each ----
    {
        const int k     = t >> 1;
        const int dbase = (t & 1) * 64;
        const float* wrow = w1 + k * 384;
        #pragma unroll
        for (int j = 0; j < 16; ++j) {
            const int d = dbase + j * 4;
            float4 wh  = *(const float4*)(wrow + d);
            float4 whu = *(const float4*)(wrow + 256 + d);
            bf16x4 o;
            o[0] = (bf16)(wh.x + ush[d + 0] * whu.x);
            o[1] = (bf16)(wh.y + ush[d + 1] * whu.y);
            o[2] = (bf16)(wh.z + ush[d + 2] * whu.z);
            o[3] = (bf16)(wh.w + ush[d + 3] * whu.w);
            *(bf16x4*)&weff[k * LDH + d] = o;
        }
    }
    // ---- bias[k] = b1[k] + sum_d u[d]*w_u[k][d]  (fp32 exact) ----
    if (t < HID) {
        const float* wrow = w1 + t * 384 + 128;
        float acc = 0.f;
        #pragma unroll 8
        for (int d = 0; d < 128; d += 4) {
            float4 wu = *(const float4*)(wrow + d);
            acc += wu.x * ush[d] + wu.y * ush[d + 1] + wu.z * ush[d + 2] + wu.w * ush[d + 3];
        }
        bias_sh[t] = b1[t] + acc;
    }
    __syncthreads();   // last barrier in the kernel

    const int lane = t & 63;
    const int wv   = t >> 6;      // wave -> c rows [wv*128, wv*128+128)
    const int col  = lane & 15;
    const int quad = lane >> 4;

    // ---- lifetime-cached B fragments: B[kdim=quad*8+j][n] = W_eff[n*16+col][kdim] ----
    bf16x8 bfrag[4][8];
    #pragma unroll
    for (int ks = 0; ks < 4; ++ks)
        #pragma unroll
        for (int n = 0; n < 8; ++n)
            bfrag[ks][n] = *(const bf16x8*)&weff[(n * 16 + col) * LDH + ks * 32 + quad * 8];

    float bias_l[8], w2_l[8];
    #pragma unroll
    for (int n = 0; n < 8; ++n) {
        bias_l[n] = bias_sh[n * 16 + col];
        w2_l[n]   = w2sh[n * 16 + col];
    }
    const float b2v = b2[0];

    const float* hbase = hptr + bi * (CDIM * HID);
    float*       obase = out + (bi * CDIM) * QDIM + qi;

    #pragma unroll 2
    for (int rt = 0; rt < 8; ++rt) {
        const int c0 = wv * 128 + rt * 16;
        const float* arow = hbase + (c0 + col) * HID;  // ks offsets become load immediates

        f32x4 acc[8];
        #pragma unroll
        for (int n = 0; n < 8; ++n) acc[n] = (f32x4){0.f, 0.f, 0.f, 0.f};

        #pragma unroll
        for (int ks = 0; ks < 4; ++ks) {
            // A[m=col][kdim=quad*8+j] from global fp32, inline cvt to bf16
            const float* ap = arow + ks * 32 + quad * 8;
            float4 v0 = *(const float4*)(ap);
            float4 v1 = *(const float4*)(ap + 4);
            bf16x8 a;
            a[0] = (bf16)v0.x; a[1] = (bf16)v0.y; a[2] = (bf16)v0.z; a[3] = (bf16)v0.w;
            a[4] = (bf16)v1.x; a[5] = (bf16)v1.y; a[6] = (bf16)v1.z; a[7] = (bf16)v1.w;
            #pragma unroll
            for (int n = 0; n < 8; ++n)
                acc[n] = __builtin_amdgcn_mfma_f32_16x16x32_bf16(a, bfrag[ks][n], acc[n], 0, 0, 0);
        }

        // ---- fused epilogue: relu(+bias).w2, 16-lane reduce, relu(+b2) ----
        // D layout: row = quad*4 + reg, colk = n*16 + col
        float s0 = 0.f, s1 = 0.f, s2 = 0.f, s3 = 0.f;
        #pragma unroll
        for (int n = 0; n < 8; ++n) {
            const float bl = bias_l[n], wl = w2_l[n];
            s0 += fmaxf(acc[n][0] + bl, 0.f) * wl;
            s1 += fmaxf(acc[n][1] + bl, 0.f) * wl;
            s2 += fmaxf(acc[n][2] + bl, 0.f) * wl;
            s3 += fmaxf(acc[n][3] + bl, 0.f) * wl;
        }
        #pragma unroll
        for (int off = 1; off < 16; off <<= 1) {
            s0 += __shfl_xor(s0, off, 64);
            s1 += __shfl_xor(s1, off, 64);
            s2 += __shfl_xor(s2, off, 64);
            s3 += __shfl_xor(s3, off, 64);
        }
        if (col < 4) {
            const float sv = col == 0 ? s0 : col == 1 ? s1 : col == 2 ? s2 : s3;
            const int crow = c0 + quad * 4 + col;
            obase[crow * QDIM] = fmaxf(sv + b2v, 0.f);
        }
    }
}

extern "C" void kernel_launch(void* const* d_in, const int* in_sizes, int n_in,
                              void* d_out, int out_size, void* d_ws, size_t ws_size,
                              hipStream_t stream) {
    const float* h  = (const float*)d_in[0];
    const float* u  = (const float*)d_in[1];
    const float* w1 = (const float*)d_in[2];
    const float* b1 = (const float*)d_in[3];
    const float* w2 = (const float*)d_in[4];
    const float* b2 = (const float*)d_in[5];
    float* out = (float*)d_out;

    sim_kernel<<<dim3(BSZ * QDIM), dim3(256), 0, stream>>>(h, u, w1, b1, w2, b2, out);
}

// Round 4
// 91.743 us; speedup vs baseline: 1.0520x; 1.0520x over previous
//
#include <hip/hip_runtime.h>
#include <hip/hip_bf16.h>

typedef __bf16 bf16;
typedef __bf16 bf16x4 __attribute__((ext_vector_type(4)));
typedef __bf16 bf16x8 __attribute__((ext_vector_type(8)));
typedef float  f32x4  __attribute__((ext_vector_type(4)));

#define HID   128
#define BSZ   8
#define CDIM  512
#define QDIM  64
#define LDH   136   // LDS leading dim (bf16): 272 B = 17*16 -> b128-aligned rows, non-pow2 bank stride

// One WG per (b,q), XCD-swizzled so all 64 same-b WGs land on one XCD (h[b]
// fetched from HBM once, L2-served after). GEMM computed TRANSPOSED:
// D'[k_out][c] = W_eff · h^T with A = W_eff (lifetime-cached in 128 VGPRs,
// pinned by waves_per_eu(2,2) so the allocator can't sink the loads — R3's
// VGPR_Count=108 showed it re-reading LDS every iteration = LDS-pipe-bound),
// B = h streamed from global with inline bf16 cvt. Epilogue reduction over
// k_out is in-lane (32 fma) + 2 shuffles. Zero LDS / zero barriers in loop.
__global__ __launch_bounds__(256) __attribute__((amdgpu_waves_per_eu(2, 2)))
void sim_kernel(const float* __restrict__ hptr,
                const float* __restrict__ uptr,
                const float* __restrict__ w1,
                const float* __restrict__ b1,
                const float* __restrict__ w2,
                const float* __restrict__ b2,
                float* __restrict__ out)
{
    __shared__ __align__(16) bf16  weff[HID * LDH];   // [k_out][d]
    __shared__ __align__(16) float ush[HID];
    __shared__ __align__(16) float bias_sh[HID];
    __shared__ __align__(16) float w2sh[HID];

    const int t  = threadIdx.x;
    const int bi = blockIdx.x & 7;    // XCD swizzle: blockIdx%8 ~ XCD id
    const int qi = blockIdx.x >> 3;

    const float* uvec = uptr + (bi * QDIM + qi) * HID;

    if (t < HID) {
        ush[t]  = uvec[t];
        w2sh[t] = w2[t];
    }
    __syncthreads();

    // ---- build W_eff[k][d] = w_h[k][d] + u[d]*w_hu[k][d] (bf16) ----
    {
        const int k     = t >> 1;
        const int dbase = (t & 1) * 64;
        const float* wrow = w1 + k * 384;
        #pragma unroll
        for (int j = 0; j < 16; ++j) {
            const int d = dbase + j * 4;
            float4 wh  = *(const float4*)(wrow + d);
            float4 whu = *(const float4*)(wrow + 256 + d);
            bf16x4 o;
            o[0] = (bf16)(wh.x + ush[d + 0] * whu.x);
            o[1] = (bf16)(wh.y + ush[d + 1] * whu.y);
            o[2] = (bf16)(wh.z + ush[d + 2] * whu.z);
            o[3] = (bf16)(wh.w + ush[d + 3] * whu.w);
            *(bf16x4*)&weff[k * LDH + d] = o;
        }
    }
    // ---- bias[k] = b1[k] + sum_d u[d]*w_u[k][d]  (fp32 exact) ----
    if (t < HID) {
        const float* wrow = w1 + t * 384 + 128;
        float acc = 0.f;
        #pragma unroll 8
        for (int d = 0; d < 128; d += 4) {
            float4 wu = *(const float4*)(wrow + d);
            acc += wu.x * ush[d] + wu.y * ush[d + 1] + wu.z * ush[d + 2] + wu.w * ush[d + 3];
        }
        bias_sh[t] = b1[t] + acc;
    }
    __syncthreads();   // last barrier in the kernel

    const int lane = t & 63;
    const int wv   = t >> 6;      // wave -> c rows [wv*128, wv*128+128)
    const int col  = lane & 15;
    const int quad = lane >> 4;

    // ---- lifetime-cached A fragments (pinned in VGPRs):
    //      A[m=col][k=quad*8+j] = W_eff[mt*16+col][ks*32+quad*8+j] ----
    bf16x8 afrag[4][8];           // [ks][mtile] = 128 VGPRs
    #pragma unroll
    for (int ks = 0; ks < 4; ++ks)
        #pragma unroll
        for (int mt = 0; mt < 8; ++mt)
            afrag[ks][mt] = *(const bf16x8*)&weff[(mt * 16 + col) * LDH + ks * 32 + quad * 8];

    // bias/w2 per lane: k_out = mt*16 + quad*4 + r  (f32x4 per mtile)
    f32x4 bias4[8], w24[8];
    #pragma unroll
    for (int mt = 0; mt < 8; ++mt) {
        bias4[mt] = *(const f32x4*)&bias_sh[mt * 16 + quad * 4];
        w24[mt]   = *(const f32x4*)&w2sh[mt * 16 + quad * 4];
    }
    const float b2v = b2[0];

    const float* hb    = hptr + bi * (CDIM * HID);
    float*       obase = out + (bi * CDIM) * QDIM + qi;

    for (int chunk = 0; chunk < 8; ++chunk) {
        const int c0 = wv * 128 + chunk * 16;
        const float* brow = hb + (c0 + col) * HID + quad * 8;

        // acc pre-initialized with bias: D = A*B + C gives l1 = h.W_eff^T + bias
        f32x4 acc[8];
        #pragma unroll
        for (int mt = 0; mt < 8; ++mt) acc[mt] = bias4[mt];

        #pragma unroll
        for (int ks = 0; ks < 4; ++ks) {
            // B[k=quad*8+j][n=col] = h[c0+col][ks*32+quad*8+j], inline bf16 cvt
            float4 v0 = *(const float4*)(brow + ks * 32);
            float4 v1 = *(const float4*)(brow + ks * 32 + 4);
            bf16x8 b;
            b[0] = (bf16)v0.x; b[1] = (bf16)v0.y; b[2] = (bf16)v0.z; b[3] = (bf16)v0.w;
            b[4] = (bf16)v1.x; b[5] = (bf16)v1.y; b[6] = (bf16)v1.z; b[7] = (bf16)v1.w;
            #pragma unroll
            for (int mt = 0; mt < 8; ++mt)
                acc[mt] = __builtin_amdgcn_mfma_f32_16x16x32_bf16(afrag[ks][mt], b, acc[mt], 0, 0, 0);
        }

        // ---- epilogue: s(c) = sum_k relu(l1[k,c]) * w2[k] ----
        // acc[mt][r] holds l1[k_out = mt*16+quad*4+r][c = c0+col] (bias included)
        float s = 0.f;
        #pragma unroll
        for (int mt = 0; mt < 8; ++mt) {
            s += fmaxf(acc[mt][0], 0.f) * w24[mt][0];
            s += fmaxf(acc[mt][1], 0.f) * w24[mt][1];
            s += fmaxf(acc[mt][2], 0.f) * w24[mt][2];
            s += fmaxf(acc[mt][3], 0.f) * w24[mt][3];
        }
        // sum the 4 quads (k_out groups); col is invariant under xor 16/32
        s += __shfl_xor(s, 16, 64);
        s += __shfl_xor(s, 32, 64);
        if (lane < 16)
            obase[(c0 + col) * QDIM] = fmaxf(s + b2v, 0.f);
    }
}

extern "C" void kernel_launch(void* const* d_in, const int* in_sizes, int n_in,
                              void* d_out, int out_size, void* d_ws, size_t ws_size,
                              hipStream_t stream) {
    const float* h  = (const float*)d_in[0];
    const float* u  = (const float*)d_in[1];
    const float* w1 = (const float*)d_in[2];
    const float* b1 = (const float*)d_in[3];
    const float* w2 = (const float*)d_in[4];
    const float* b2 = (const float*)d_in[5];
    float* out = (float*)d_out;

    sim_kernel<<<dim3(BSZ * QDIM), dim3(256), 0, stream>>>(h, u, w1, b1, w2, b2, out);
}

// Round 5
// 83.475 us; speedup vs baseline: 1.1562x; 1.0991x over previous
//
#include <hip/hip_runtime.h>
#include <hip/hip_bf16.h>

typedef __bf16 bf16;
typedef __bf16 bf16x4 __attribute__((ext_vector_type(4)));
typedef __bf16 bf16x8 __attribute__((ext_vector_type(8)));
typedef float  f32x4  __attribute__((ext_vector_type(4)));

#define HID   128
#define BSZ   8
#define CDIM  512
#define QDIM  64
#define LDH   136   // LDS leading dim (bf16): 272 B rows, b128-aligned, non-pow2 bank stride

// d_ws layout (bytes) — total ~1.4 MB dirty (R2's 18 MB correlated with slower
// poison fills; keep the footprint minimal)
#define HBF_OFF   0u        // h bf16:   8*512*128*2   = 1,048,576
#define WHHU_OFF  1048576u  // (wh,whu) interleaved bf16: 128*128*2*2 = 65,536
#define BIAS_OFF  1114112u  // bias fp32: 8*64*128*4   =   262,144

// ---------------------------------------------------------------------------
// Prep: blk<128 h fp32->bf16 | blk<136 repack w_h/w_hu interleaved bf16 |
//       else bias[b,q,k] = b1[k] + u[b,q].w_u[k] (fp32 exact).
// Removes per-WG fp32 w1 (192 KB) + fp32 h (256 KB) redundant reads from main.
// ---------------------------------------------------------------------------
__global__ __launch_bounds__(256)
void prep_kernel(const float* __restrict__ hptr,
                 const float* __restrict__ uptr,
                 const float* __restrict__ w1,
                 const float* __restrict__ b1,
                 char* __restrict__ ws)
{
    const int t   = threadIdx.x;
    const int blk = blockIdx.x;

    if (blk < 128) {                    // ---- h -> bf16, coalesced ----
        bf16* hbf = (bf16*)(ws + HBF_OFF);
        const int base4 = blk * 1024;   // float4 index
        #pragma unroll
        for (int i = 0; i < 4; ++i) {
            const int f4 = base4 + i * 256 + t;
            float4 v = *(const float4*)(hptr + f4 * 4);
            bf16x4 o;
            o[0] = (bf16)v.x; o[1] = (bf16)v.y; o[2] = (bf16)v.z; o[3] = (bf16)v.w;
            *(bf16x4*)&hbf[f4 * 4] = o;
        }
    } else if (blk < 136) {             // ---- repack (wh,whu) interleaved ----
        bf16* whhu = (bf16*)(ws + WHHU_OFF);
        const int kg = blk - 128;       // 16 k-rows per block
        #pragma unroll
        for (int i = 0; i < 8; ++i) {
            const int idx = i * 256 + t;          // 0..2047 = 16k x 128d
            const int kl = idx >> 7, d = idx & 127;
            const int k  = kg * 16 + kl;
            const float wh  = w1[k * 384 + d];
            const float whu = w1[k * 384 + 256 + d];
            bf16* p = &whhu[k * 256 + d * 2];
            p[0] = (bf16)wh;
            p[1] = (bf16)whu;
        }
    } else {                            // ---- bias (fp32 exact) ----
        __shared__ float u_sh[QDIM * 132];
        __shared__ float wu_sh[16 * 132];
        const int id = blk - 136;       // 0..63
        const int b  = id >> 3;
        const int kg = id & 7;          // 16 k-rows
        const float* ub = uptr + b * QDIM * HID;
        #pragma unroll
        for (int i = 0; i < 8; ++i) {   // u[b]: 2048 float4
            const int f4 = i * 256 + t;
            const int q = f4 >> 5, c4 = f4 & 31;
            *(float4*)&u_sh[q * 132 + c4 * 4] = *(const float4*)(ub + f4 * 4);
        }
        #pragma unroll
        for (int i = 0; i < 2; ++i) {   // w_u rows kg*16..+15: 512 float4
            const int f4 = i * 256 + t;
            const int r = f4 >> 5, c4 = f4 & 31;
            *(float4*)&wu_sh[r * 132 + c4 * 4] =
                *(const float4*)(w1 + (kg * 16 + r) * 384 + 128 + c4 * 4);
        }
        __syncthreads();
        float* bias = (float*)(ws + BIAS_OFF);
        #pragma unroll
        for (int i = 0; i < 4; ++i) {   // 1024 dots = 64q x 16k
            const int p = i * 256 + t;
            const int q = p >> 4, kk = p & 15;
            const float* uu = &u_sh[q * 132];
            const float* wu = &wu_sh[kk * 132];
            float acc = 0.f;
            #pragma unroll 8
            for (int d = 0; d < 128; d += 4) {
                f32x4 a = *(const f32x4*)&uu[d];
                f32x4 w = *(const f32x4*)&wu[d];
                acc += a[0]*w[0] + a[1]*w[1] + a[2]*w[2] + a[3]*w[3];
            }
            bias[(b * QDIM + q) * HID + kg * 16 + kk] = b1[kg * 16 + kk] + acc;
        }
    }
}

// ---------------------------------------------------------------------------
// Main: one WG per (b,q), XCD-swizzled (all 64 same-b WGs on one XCD so h[b]
// is HBM-fetched once, L2-served after). Transposed GEMM: A = W_eff
// (lifetime-cached 128 VGPRs, pinned by waves_per_eu(2,2) — R3's VGPR=108
// showed the allocator sinking these to per-iter LDS reads = LDS-pipe-bound),
// B = h streamed bf16 from ws (no cvt in loop). bias preloaded fp32 into the
// MFMA C operand. Zero LDS / zero barriers in the main loop.
// ---------------------------------------------------------------------------
__global__ __launch_bounds__(256) __attribute__((amdgpu_waves_per_eu(2, 2)))
void sim_kernel(const char* __restrict__ ws,
                const float* __restrict__ uptr,
                const float* __restrict__ w2,
                const float* __restrict__ b2,
                float* __restrict__ out)
{
    __shared__ __align__(16) bf16  weff[HID * LDH];   // [k_out][d]
    __shared__ __align__(16) float ush[HID];

    const int t  = threadIdx.x;
    const int bi = blockIdx.x & 7;    // XCD swizzle
    const int qi = blockIdx.x >> 3;

    const float* uvec = uptr + (bi * QDIM + qi) * HID;
    if (t < HID) ush[t] = uvec[t];
    __syncthreads();

    // ---- build W_eff[k][d] = wh[k][d] + u[d]*whu[k][d] from interleaved bf16 ----
    {
        const bf16* whhu = (const bf16*)(ws + WHHU_OFF);
        const int k     = t >> 1;
        const int dbase = (t & 1) * 64;
        #pragma unroll
        for (int j = 0; j < 16; ++j) {
            const int d = dbase + j * 4;
            bf16x8 pw = *(const bf16x8*)(whhu + k * 256 + d * 2);  // 4 (wh,whu) pairs
            bf16x4 o;
            o[0] = (bf16)((float)pw[0] + ush[d + 0] * (float)pw[1]);
            o[1] = (bf16)((float)pw[2] + ush[d + 1] * (float)pw[3]);
            o[2] = (bf16)((float)pw[4] + ush[d + 2] * (float)pw[5]);
            o[3] = (bf16)((float)pw[6] + ush[d + 3] * (float)pw[7]);
            *(bf16x4*)&weff[k * LDH + d] = o;
        }
    }
    __syncthreads();   // last barrier in the kernel

    const int lane = t & 63;
    const int wv   = t >> 6;
    const int col  = lane & 15;
    const int quad = lane >> 4;

    // ---- lifetime-cached A fragments: A[m=col][k=quad*8+j] ----
    bf16x8 afrag[4][8];               // [ks][mtile] = 128 VGPRs, pinned
    #pragma unroll
    for (int ks = 0; ks < 4; ++ks)
        #pragma unroll
        for (int mt = 0; mt < 8; ++mt)
            afrag[ks][mt] = *(const bf16x8*)&weff[(mt * 16 + col) * LDH + ks * 32 + quad * 8];

    // bias/w2 per lane straight from global: k_out = mt*16 + quad*4 + r
    const float* bias_row = (const float*)(ws + BIAS_OFF) + (bi * QDIM + qi) * HID;
    f32x4 bias4[8], w24[8];
    #pragma unroll
    for (int mt = 0; mt < 8; ++mt) {
        bias4[mt] = *(const f32x4*)&bias_row[mt * 16 + quad * 4];
        w24[mt]   = *(const f32x4*)&w2[mt * 16 + quad * 4];
    }
    const float b2v = b2[0];

    const bf16* hb    = (const bf16*)(ws + HBF_OFF) + bi * (CDIM * HID);
    float*      obase = out + (bi * CDIM) * QDIM + qi;

    for (int chunk = 0; chunk < 8; ++chunk) {
        const int c0 = wv * 128 + chunk * 16;
        const bf16* brow = hb + (c0 + col) * HID + quad * 8;

        // C preloaded with bias: D = A*B + C gives l1 directly
        f32x4 acc[8];
        #pragma unroll
        for (int mt = 0; mt < 8; ++mt) acc[mt] = bias4[mt];

        #pragma unroll
        for (int ks = 0; ks < 4; ++ks) {
            bf16x8 b = *(const bf16x8*)(brow + ks * 32);   // 16 B, no cvt
            #pragma unroll
            for (int mt = 0; mt < 8; ++mt)
                acc[mt] = __builtin_amdgcn_mfma_f32_16x16x32_bf16(afrag[ks][mt], b, acc[mt], 0, 0, 0);
        }

        // ---- epilogue: s(c) = sum_k relu(l1[k,c]) * w2[k] ----
        float s = 0.f;
        #pragma unroll
        for (int mt = 0; mt < 8; ++mt) {
            s += fmaxf(acc[mt][0], 0.f) * w24[mt][0];
            s += fmaxf(acc[mt][1], 0.f) * w24[mt][1];
            s += fmaxf(acc[mt][2], 0.f) * w24[mt][2];
            s += fmaxf(acc[mt][3], 0.f) * w24[mt][3];
        }
        s += __shfl_xor(s, 16, 64);   // reduce the 4 quad-groups of k_out
        s += __shfl_xor(s, 32, 64);
        if (lane < 16)
            obase[(c0 + col) * QDIM] = fmaxf(s + b2v, 0.f);
    }
}

extern "C" void kernel_launch(void* const* d_in, const int* in_sizes, int n_in,
                              void* d_out, int out_size, void* d_ws, size_t ws_size,
                              hipStream_t stream) {
    const float* h  = (const float*)d_in[0];
    const float* u  = (const float*)d_in[1];
    const float* w1 = (const float*)d_in[2];
    const float* b1 = (const float*)d_in[3];
    const float* w2 = (const float*)d_in[4];
    const float* b2 = (const float*)d_in[5];
    float* out = (float*)d_out;
    char*  ws  = (char*)d_ws;

    prep_kernel<<<dim3(200), dim3(256), 0, stream>>>(h, u, w1, b1, ws);
    sim_kernel<<<dim3(BSZ * QDIM), dim3(256), 0, stream>>>(ws, u, w2, b2, out);
}